// Round 7
// baseline (14138.651 us; speedup 1.0000x reference)
//
#include <hip/hip_runtime.h>
#include <math.h>

#define B 512
#define S 64
#define T 32
#define E 512
#define H 1024
#define VOUTD 128
#define H2 (2*H)
#define H3 (3*H)
#define H6 (6*H)
#define LP 40   // LDS row pitch (elems): 80 B = 16B-aligned, low bank aliasing

typedef unsigned short ushortT;
typedef unsigned int uintT;
typedef __attribute__((ext_vector_type(8))) short short8;
typedef __attribute__((ext_vector_type(4))) float floatx4;

__device__ __forceinline__ float sigmoidf_(float x) { return 1.0f / (1.0f + expf(-x)); }

// ===========================================================================
// Split fp32 -> bf16 hi/lo planes. hi = trunc16(x), lo = trunc16(x - hi).
// ===========================================================================
__global__ __launch_bounds__(256) void split_bf16(
    const float4* __restrict__ x, uint2* __restrict__ hi, uint2* __restrict__ lo, int n4)
{
    int i = blockIdx.x * 256 + threadIdx.x;
    if (i >= n4) return;
    float4 v = x[i];
    uintT ux = __float_as_uint(v.x), uy = __float_as_uint(v.y);
    uintT uz = __float_as_uint(v.z), uw = __float_as_uint(v.w);
    uintT lx = __float_as_uint(v.x - __uint_as_float(ux & 0xFFFF0000u)) >> 16;
    uintT ly = __float_as_uint(v.y - __uint_as_float(uy & 0xFFFF0000u)) >> 16;
    uintT lz = __float_as_uint(v.z - __uint_as_float(uz & 0xFFFF0000u)) >> 16;
    uintT lw = __float_as_uint(v.w - __uint_as_float(uw & 0xFFFF0000u)) >> 16;
    hi[i] = make_uint2((ux >> 16) | (uy & 0xFFFF0000u), (uz >> 16) | (uw & 0xFFFF0000u));
    lo[i] = make_uint2(lx | (ly << 16), lz | (lw << 16));
}

__global__ __launch_bounds__(256) void zero16(uint4* __restrict__ p, int n)
{
    int i = blockIdx.x * 256 + threadIdx.x;
    if (i < n) p[i] = make_uint4(0u, 0u, 0u, 0u);
}

// ===========================================================================
// FUSED GRU step, encoder (fwd+bwd). One block = 64 rows x 64 j-cols, ALL
// three gates (B-tile = W rows {j, H+j, 2H+j} = 192 rows), full K=H. gh is
// never materialized: gate applied in registers, h written directly.
// Wave w owns col-tiles {w, w+4, w+8} -> r/z/n for jj land in same lane/reg.
// Grid 256 blocks 1-D: xcd=bid&7, g=bid>>3, jt=xcd+8*(g&1), mt=g>>1 — same-j
// blocks share an XCD (weight slice ~3 MB L2-resident across steps).
// 3-term split-bf16: Ah*Bh + Ah*Bl + Al*Bh (fp32-class).
// ===========================================================================
__global__ __launch_bounds__(256) void gru_step_enc(
    const ushortT* __restrict__ Ahi, const ushortT* __restrict__ Alo,   // h planes 1024x1024
    const ushortT* __restrict__ Whi_f, const ushortT* __restrict__ Wlo_f,
    const ushortT* __restrict__ Whi_b, const ushortT* __restrict__ Wlo_b,
    const float* __restrict__ giTabF, const float* __restrict__ giTabB,
    const int* __restrict__ src, int s,
    const float* __restrict__ bhF, const float* __restrict__ bhB,
    const float* __restrict__ hprev,
    float* __restrict__ hout, ushortT* __restrict__ hout_hi, ushortT* __restrict__ hout_lo)
{
    __shared__ ushortT sAh[64 * LP], sAl[64 * LP];
    __shared__ ushortT sBh[192 * LP], sBl[192 * LP];

    const int t = threadIdx.x, lane = t & 63, w = t >> 6;
    const int bid = blockIdx.x;
    const int xcd = bid & 7, g = bid >> 3;
    const int jt = xcd + 8 * (g & 1);      // 0..15
    const int mt = g >> 1;                 // 0..15
    const int j0 = jt * 64, m0 = mt * 64;
    const bool bwd = (m0 >= B);
    const ushortT* Whi = bwd ? Whi_b : Whi_f;
    const ushortT* Wlo = bwd ? Wlo_b : Wlo_f;
    const float* giTab = bwd ? giTabB : giTabF;
    const float* bh    = bwd ? bhB : bhF;

    // staging: thread t covers A row t>>2 seg (t&3)*8; B rows q*64 + (t>>2)
    const int rsA = t >> 2, sgA = (t & 3) * 8;
    const ushortT* gAh = Ahi + (size_t)(m0 + rsA) * H + sgA;
    const ushortT* gAl = Alo + (size_t)(m0 + rsA) * H + sgA;
    const int ldsA = rsA * LP + sgA;
    const ushortT* gBh[3]; const ushortT* gBl[3]; int ldsB[3];
#pragma unroll
    for (int q = 0; q < 3; ++q) {
        int wrow = q * H + j0 + rsA;
        gBh[q] = Whi + (size_t)wrow * H + sgA;
        gBl[q] = Wlo + (size_t)wrow * H + sgA;
        ldsB[q] = (q * 64 + rsA) * LP + sgA;
    }

    const int koff = (lane >> 4) * 8;
    const int frow = lane & 15;

    floatx4 acc[3][4];
#pragma unroll
    for (int q = 0; q < 3; ++q)
#pragma unroll
        for (int i = 0; i < 4; ++i) acc[q][i] = (floatx4){0.f, 0.f, 0.f, 0.f};

    uint4 vA[2], vB[6];
    vA[0] = *(const uint4*)gAh; vA[1] = *(const uint4*)gAl;
#pragma unroll
    for (int q = 0; q < 3; ++q) {
        vB[2 * q]     = *(const uint4*)gBh[q];
        vB[2 * q + 1] = *(const uint4*)gBl[q];
    }
    *(uint4*)&sAh[ldsA] = vA[0]; *(uint4*)&sAl[ldsA] = vA[1];
#pragma unroll
    for (int q = 0; q < 3; ++q) {
        *(uint4*)&sBh[ldsB[q]] = vB[2 * q];
        *(uint4*)&sBl[ldsB[q]] = vB[2 * q + 1];
    }
    __syncthreads();

    const int nCh = H / 32;
    for (int ck = 0; ck < nCh; ++ck) {
        const bool hasNext = (ck + 1 < nCh);

        short8 ah[4], al[4], bhf[3], blf[3];
#pragma unroll
        for (int i = 0; i < 4; ++i) {
            ah[i] = *(const short8*)&sAh[(i * 16 + frow) * LP + koff];
            al[i] = *(const short8*)&sAl[(i * 16 + frow) * LP + koff];
        }
#pragma unroll
        for (int q = 0; q < 3; ++q) {
            int row = q * 64 + 16 * w + frow;
            bhf[q] = *(const short8*)&sBh[row * LP + koff];
            blf[q] = *(const short8*)&sBl[row * LP + koff];
        }

        if (hasNext) {
            int k0 = (ck + 1) * 32;
            vA[0] = *(const uint4*)(gAh + k0); vA[1] = *(const uint4*)(gAl + k0);
#pragma unroll
            for (int q = 0; q < 3; ++q) {
                vB[2 * q]     = *(const uint4*)(gBh[q] + k0);
                vB[2 * q + 1] = *(const uint4*)(gBl[q] + k0);
            }
        }

#pragma unroll
        for (int q = 0; q < 3; ++q)
#pragma unroll
            for (int i = 0; i < 4; ++i) {
                acc[q][i] = __builtin_amdgcn_mfma_f32_16x16x32_bf16(ah[i], bhf[q], acc[q][i], 0, 0, 0);
                acc[q][i] = __builtin_amdgcn_mfma_f32_16x16x32_bf16(ah[i], blf[q], acc[q][i], 0, 0, 0);
                acc[q][i] = __builtin_amdgcn_mfma_f32_16x16x32_bf16(al[i], bhf[q], acc[q][i], 0, 0, 0);
            }

        if (hasNext) {
            __syncthreads();
            *(uint4*)&sAh[ldsA] = vA[0]; *(uint4*)&sAl[ldsA] = vA[1];
#pragma unroll
            for (int q = 0; q < 3; ++q) {
                *(uint4*)&sBh[ldsB[q]] = vB[2 * q];
                *(uint4*)&sBl[ldsB[q]] = vB[2 * q + 1];
            }
            __syncthreads();
        }
    }

    // epilogue: C/D col = lane&15 (jj), row = (lane>>4)*4 + reg (m). Gate in regs.
    const int jj = j0 + 16 * w + frow;
    const float bhr = bh[jj], bhz = bh[H + jj], bhn = bh[2 * H + jj];
#pragma unroll
    for (int i = 0; i < 4; ++i) {
        int mbase = m0 + i * 16 + (lane >> 4) * 4;
#pragma unroll
        for (int r = 0; r < 4; ++r) {
            int m = mbase + r;
            int b = m & (B - 1);
            int tk = src[b * S + (bwd ? (S - 1 - s) : s)];
            const float* gi = giTab + (size_t)tk * H3;
            float rr = sigmoidf_(gi[jj] + acc[0][i][r] + bhr);
            float zz = sigmoidf_(gi[H + jj] + acc[1][i][r] + bhz);
            float nn = tanhf(gi[2 * H + jj] + rr * (acc[2][i][r] + bhn));
            float hv = hprev[(size_t)m * H + jj];
            float o = (1.f - zz) * nn + zz * hv;
            hout[(size_t)m * H + jj] = o;
            uintT u = __float_as_uint(o);
            hout_hi[(size_t)m * H + jj] = (ushortT)(u >> 16);
            hout_lo[(size_t)m * H + jj] =
                (ushortT)(__float_as_uint(o - __uint_as_float(u & 0xFFFF0000u)) >> 16);
        }
    }
}

// ===========================================================================
// FUSED GRU step, decoder. 64 rows x 64 j (of H2) x 3 gates, K=H2=2048.
// Grid 256: jt = xcd + 8*(g&3) (0..31), mt = g>>2 (0..7).
// ===========================================================================
__global__ __launch_bounds__(256) void gru_step_dec(
    const ushortT* __restrict__ Ahi, const ushortT* __restrict__ Alo,   // hh planes 512x2048
    const ushortT* __restrict__ Whi, const ushortT* __restrict__ Wlo,   // 6144x2048
    const float* __restrict__ giTabD, const int* __restrict__ tok,
    const float* __restrict__ bh,
    const float* __restrict__ hprev,
    float* __restrict__ hout, ushortT* __restrict__ hout_hi, ushortT* __restrict__ hout_lo)
{
    __shared__ ushortT sAh[64 * LP], sAl[64 * LP];
    __shared__ ushortT sBh[192 * LP], sBl[192 * LP];

    const int t = threadIdx.x, lane = t & 63, w = t >> 6;
    const int bid = blockIdx.x;
    const int xcd = bid & 7, g = bid >> 3;
    const int jt = xcd + 8 * (g & 3);      // 0..31
    const int mt = g >> 2;                 // 0..7
    const int j0 = jt * 64, m0 = mt * 64;

    const int rsA = t >> 2, sgA = (t & 3) * 8;
    const ushortT* gAh = Ahi + (size_t)(m0 + rsA) * H2 + sgA;
    const ushortT* gAl = Alo + (size_t)(m0 + rsA) * H2 + sgA;
    const int ldsA = rsA * LP + sgA;
    const ushortT* gBh[3]; const ushortT* gBl[3]; int ldsB[3];
#pragma unroll
    for (int q = 0; q < 3; ++q) {
        int wrow = q * H2 + j0 + rsA;
        gBh[q] = Whi + (size_t)wrow * H2 + sgA;
        gBl[q] = Wlo + (size_t)wrow * H2 + sgA;
        ldsB[q] = (q * 64 + rsA) * LP + sgA;
    }

    const int koff = (lane >> 4) * 8;
    const int frow = lane & 15;

    floatx4 acc[3][4];
#pragma unroll
    for (int q = 0; q < 3; ++q)
#pragma unroll
        for (int i = 0; i < 4; ++i) acc[q][i] = (floatx4){0.f, 0.f, 0.f, 0.f};

    uint4 vA[2], vB[6];
    vA[0] = *(const uint4*)gAh; vA[1] = *(const uint4*)gAl;
#pragma unroll
    for (int q = 0; q < 3; ++q) {
        vB[2 * q]     = *(const uint4*)gBh[q];
        vB[2 * q + 1] = *(const uint4*)gBl[q];
    }
    *(uint4*)&sAh[ldsA] = vA[0]; *(uint4*)&sAl[ldsA] = vA[1];
#pragma unroll
    for (int q = 0; q < 3; ++q) {
        *(uint4*)&sBh[ldsB[q]] = vB[2 * q];
        *(uint4*)&sBl[ldsB[q]] = vB[2 * q + 1];
    }
    __syncthreads();

    const int nCh = H2 / 32;
    for (int ck = 0; ck < nCh; ++ck) {
        const bool hasNext = (ck + 1 < nCh);

        short8 ah[4], al[4], bhf[3], blf[3];
#pragma unroll
        for (int i = 0; i < 4; ++i) {
            ah[i] = *(const short8*)&sAh[(i * 16 + frow) * LP + koff];
            al[i] = *(const short8*)&sAl[(i * 16 + frow) * LP + koff];
        }
#pragma unroll
        for (int q = 0; q < 3; ++q) {
            int row = q * 64 + 16 * w + frow;
            bhf[q] = *(const short8*)&sBh[row * LP + koff];
            blf[q] = *(const short8*)&sBl[row * LP + koff];
        }

        if (hasNext) {
            int k0 = (ck + 1) * 32;
            vA[0] = *(const uint4*)(gAh + k0); vA[1] = *(const uint4*)(gAl + k0);
#pragma unroll
            for (int q = 0; q < 3; ++q) {
                vB[2 * q]     = *(const uint4*)(gBh[q] + k0);
                vB[2 * q + 1] = *(const uint4*)(gBl[q] + k0);
            }
        }

#pragma unroll
        for (int q = 0; q < 3; ++q)
#pragma unroll
            for (int i = 0; i < 4; ++i) {
                acc[q][i] = __builtin_amdgcn_mfma_f32_16x16x32_bf16(ah[i], bhf[q], acc[q][i], 0, 0, 0);
                acc[q][i] = __builtin_amdgcn_mfma_f32_16x16x32_bf16(ah[i], blf[q], acc[q][i], 0, 0, 0);
                acc[q][i] = __builtin_amdgcn_mfma_f32_16x16x32_bf16(al[i], bhf[q], acc[q][i], 0, 0, 0);
            }

        if (hasNext) {
            __syncthreads();
            *(uint4*)&sAh[ldsA] = vA[0]; *(uint4*)&sAl[ldsA] = vA[1];
#pragma unroll
            for (int q = 0; q < 3; ++q) {
                *(uint4*)&sBh[ldsB[q]] = vB[2 * q];
                *(uint4*)&sBl[ldsB[q]] = vB[2 * q + 1];
            }
            __syncthreads();
        }
    }

    const int jj = j0 + 16 * w + frow;
    const float bhr = bh[jj], bhz = bh[H2 + jj], bhn = bh[2 * H2 + jj];
#pragma unroll
    for (int i = 0; i < 4; ++i) {
        int mbase = m0 + i * 16 + (lane >> 4) * 4;
#pragma unroll
        for (int r = 0; r < 4; ++r) {
            int m = mbase + r;
            int tk = tok[m];
            const float* gi = giTabD + (size_t)tk * H6;
            float rr = sigmoidf_(gi[jj] + acc[0][i][r] + bhr);
            float zz = sigmoidf_(gi[H2 + jj] + acc[1][i][r] + bhz);
            float nn = tanhf(gi[2 * H2 + jj] + rr * (acc[2][i][r] + bhn));
            float hv = hprev[(size_t)m * H2 + jj];
            float o = (1.f - zz) * nn + zz * hv;
            hout[(size_t)m * H2 + jj] = o;
            uintT u = __float_as_uint(o);
            hout_hi[(size_t)m * H2 + jj] = (ushortT)(u >> 16);
            hout_lo[(size_t)m * H2 + jj] =
                (ushortT)(__float_as_uint(o - __uint_as_float(u & 0xFFFF0000u)) >> 16);
        }
    }
}

// hh[b,0:H]=h_f[b], hh[b,H:2H]=h_b[b] (+ bf16 planes); tok[b]=tgt[b,0]
__global__ __launch_bounds__(256) void init_hh_tok_split(
    const float* __restrict__ h_f, const float* __restrict__ h_b,
    const int* __restrict__ tgt, float* __restrict__ hh,
    ushortT* __restrict__ hh_hi, ushortT* __restrict__ hh_lo, int* __restrict__ tok)
{
    int i = blockIdx.x * blockDim.x + threadIdx.x;   // over B*2H
    int b = i >> 11;
    int j = i & 2047;
    float v = (j < H) ? h_f[(size_t)b * H + j] : h_b[(size_t)b * H + (j - H)];
    hh[i] = v;
    uintT u = __float_as_uint(v);
    hh_hi[i] = (ushortT)(u >> 16);
    hh_lo[i] = (ushortT)(__float_as_uint(v - __uint_as_float(u & 0xFFFF0000u)) >> 16);
    if (j == 0) tok[b] = tgt[b * T];
}

// ===========================================================================
// logits = hh @ W_fc^T + b_fc (V=128); out[b,t,:]; tok[b]=argmax (first-idx ties)
// ===========================================================================
__global__ __launch_bounds__(128) void logits_argmax(
    const float* __restrict__ hh, const float* __restrict__ W_fc,
    const float* __restrict__ b_fc, float* __restrict__ out,
    int* __restrict__ tok, int t)
{
    __shared__ float sh[H2];
    __shared__ float svals[128];
    __shared__ int   sidx[128];
    const int b = blockIdx.x;
    const int v = threadIdx.x;
    const float* hrow = hh + (size_t)b * H2;
    for (int i = v; i < H2 / 4; i += 128)
        ((float4*)sh)[i] = ((const float4*)hrow)[i];
    __syncthreads();
    const float* wrow = W_fc + (size_t)v * H2;
    float acc = b_fc[v];
    for (int k = 0; k < H2; k += 4) {
        float4 w4 = *(const float4*)(wrow + k);
        float4 h4 = *(const float4*)(sh + k);
        acc += w4.x * h4.x + w4.y * h4.y + w4.z * h4.z + w4.w * h4.w;
    }
    out[(size_t)b * ((T - 1) * VOUTD) + (size_t)t * VOUTD + v] = acc;

    svals[v] = acc; sidx[v] = v;
    __syncthreads();
    for (int off = 64; off > 0; off >>= 1) {
        if (v < off) {
            float ov = svals[v + off]; int oi = sidx[v + off];
            if (ov > svals[v] || (ov == svals[v] && oi < sidx[v])) {
                svals[v] = ov; sidx[v] = oi;
            }
        }
        __syncthreads();
    }
    if (v == 0) tok[b] = sidx[0];
}

// ===========================================================================
// fp32 vector GEMM (R1-proven): gi-table precompute + fallback path.
// ===========================================================================
__global__ __launch_bounds__(256) void gemm_bias(
    const float* __restrict__ Abase,
    const int* __restrict__ idx, int idxStride, int idxOff, int lda,
    const float* __restrict__ W, const float* __restrict__ bias,
    float* __restrict__ C, int N, int K)
{
    __shared__ float As[16][68];
    __shared__ float Ws[16][68];
    const int t = threadIdx.x;
    const int m0 = blockIdx.y * 64, n0 = blockIdx.x * 64;
    const int lr = t >> 2, lc = (t & 3) << 2;
    const int tx = t & 15, ty = t >> 4;
    const int tn0 = tx << 2, tm0 = ty << 2;
    const int arow = m0 + lr;
    const float* Aptr = idx ? (Abase + (size_t)idx[arow * idxStride + idxOff] * lda)
                            : (Abase + (size_t)arow * lda);
    const float* Wptr = W + (size_t)(n0 + lr) * K;
    float acc[4][4] = {{0.f}};
    for (int k0 = 0; k0 < K; k0 += 16) {
        float4 a4 = *(const float4*)(Aptr + k0 + lc);
        float4 w4 = *(const float4*)(Wptr + k0 + lc);
        __syncthreads();
        As[lc+0][lr] = a4.x; As[lc+1][lr] = a4.y; As[lc+2][lr] = a4.z; As[lc+3][lr] = a4.w;
        Ws[lc+0][lr] = w4.x; Ws[lc+1][lr] = w4.y; Ws[lc+2][lr] = w4.z; Ws[lc+3][lr] = w4.w;
        __syncthreads();
#pragma unroll
        for (int kk = 0; kk < 16; ++kk) {
            float4 av = *(const float4*)&As[kk][tm0];
            float4 wv = *(const float4*)&Ws[kk][tn0];
            float am[4] = {av.x, av.y, av.z, av.w};
            float wn[4] = {wv.x, wv.y, wv.z, wv.w};
#pragma unroll
            for (int i = 0; i < 4; ++i)
#pragma unroll
                for (int j = 0; j < 4; ++j) acc[i][j] += am[i] * wn[j];
        }
    }
    const float b0 = bias[n0+tn0], b1 = bias[n0+tn0+1], b2 = bias[n0+tn0+2], b3 = bias[n0+tn0+3];
#pragma unroll
    for (int i = 0; i < 4; ++i) {
        float4 o = make_float4(acc[i][0]+b0, acc[i][1]+b1, acc[i][2]+b2, acc[i][3]+b3);
        *(float4*)(C + (size_t)(m0 + tm0 + i) * N + n0 + tn0) = o;
    }
}

__global__ __launch_bounds__(256) void gemm_enc(
    const float* __restrict__ Abase, int lda, int K,
    const int* __restrict__ srcIdx, int s,
    const float* __restrict__ W1, const float* __restrict__ bias1,
    const float* __restrict__ W2, const float* __restrict__ bias2,
    float* __restrict__ C, int N)
{
    __shared__ float As[16][68];
    __shared__ float Ws[16][68];
    const int t = threadIdx.x;
    const int m0 = blockIdx.y * 64, n0 = blockIdx.x * 64;
    const bool bwd = (m0 >= B);
    const float* W = bwd ? W2 : W1;
    const float* bias = bwd ? bias2 : bias1;
    const int lr = t >> 2, lc = (t & 3) << 2;
    const int tx = t & 15, ty = t >> 4;
    const int tn0 = tx << 2, tm0 = ty << 2;
    const int arow = m0 + lr;
    const float* Aptr;
    if (srcIdx) {
        int r = arow & (B - 1);
        int sidx = bwd ? (S - 1 - s) : s;
        Aptr = Abase + (size_t)srcIdx[r * S + sidx] * lda;
    } else Aptr = Abase + (size_t)arow * lda;
    const float* Wptr = W + (size_t)(n0 + lr) * K;
    float acc[4][4] = {{0.f}};
    for (int k0 = 0; k0 < K; k0 += 16) {
        float4 a4 = *(const float4*)(Aptr + k0 + lc);
        float4 w4 = *(const float4*)(Wptr + k0 + lc);
        __syncthreads();
        As[lc+0][lr] = a4.x; As[lc+1][lr] = a4.y; As[lc+2][lr] = a4.z; As[lc+3][lr] = a4.w;
        Ws[lc+0][lr] = w4.x; Ws[lc+1][lr] = w4.y; Ws[lc+2][lr] = w4.z; Ws[lc+3][lr] = w4.w;
        __syncthreads();
#pragma unroll
        for (int kk = 0; kk < 16; ++kk) {
            float4 av = *(const float4*)&As[kk][tm0];
            float4 wv = *(const float4*)&Ws[kk][tn0];
            float am[4] = {av.x, av.y, av.z, av.w};
            float wn[4] = {wv.x, wv.y, wv.z, wv.w};
#pragma unroll
            for (int i = 0; i < 4; ++i)
#pragma unroll
                for (int j = 0; j < 4; ++j) acc[i][j] += am[i] * wn[j];
        }
    }
    const float b0 = bias[n0+tn0], b1 = bias[n0+tn0+1], b2 = bias[n0+tn0+2], b3 = bias[n0+tn0+3];
#pragma unroll
    for (int i = 0; i < 4; ++i) {
        float4 o = make_float4(acc[i][0]+b0, acc[i][1]+b1, acc[i][2]+b2, acc[i][3]+b3);
        *(float4*)(C + (size_t)(m0 + tm0 + i) * N + n0 + tn0) = o;
    }
}

__global__ __launch_bounds__(256) void gru_gate(
    const float* __restrict__ gi, const float* __restrict__ gh,
    float* __restrict__ h, int Hd)
{
    int i = blockIdx.x * blockDim.x + threadIdx.x;
    int b = i / Hd, j = i - b * Hd;
    const float* gib = gi + (size_t)b * 3 * Hd;
    const float* ghb = gh + (size_t)b * 3 * Hd;
    float r = sigmoidf_(gib[j] + ghb[j]);
    float z = sigmoidf_(gib[Hd + j] + ghb[Hd + j]);
    float n = tanhf(gib[2 * Hd + j] + r * ghb[2 * Hd + j]);
    h[i] = (1.0f - z) * n + z * h[i];
}

__global__ __launch_bounds__(256) void init_hh_tok(
    const float* __restrict__ h_f, const float* __restrict__ h_b,
    const int* __restrict__ tgt, float* __restrict__ hh, int* __restrict__ tok)
{
    int i = blockIdx.x * blockDim.x + threadIdx.x;
    int b = i >> 11, j = i & 2047;
    hh[i] = (j < H) ? h_f[(size_t)b * H + j] : h_b[(size_t)b * H + (j - H)];
    if (j == 0) tok[b] = tgt[b * T];
}

// ===========================================================================
extern "C" void kernel_launch(void* const* d_in, const int* in_sizes, int n_in,
                              void* d_out, int out_size, void* d_ws, size_t ws_size,
                              hipStream_t stream)
{
    const int*   src     = (const int*)d_in[0];
    const int*   tgt     = (const int*)d_in[1];
    const float* enc_emb = (const float*)d_in[2];
    const float* dec_emb = (const float*)d_in[3];
    const float* W_ih_f  = (const float*)d_in[4];
    const float* W_hh_f  = (const float*)d_in[5];
    const float* b_ih_f  = (const float*)d_in[6];
    const float* b_hh_f  = (const float*)d_in[7];
    const float* W_ih_b  = (const float*)d_in[8];
    const float* W_hh_b  = (const float*)d_in[9];
    const float* b_ih_b  = (const float*)d_in[10];
    const float* b_hh_b  = (const float*)d_in[11];
    const float* W_ih_d  = (const float*)d_in[12];
    const float* W_hh_d  = (const float*)d_in[13];
    const float* b_ih_d  = (const float*)d_in[14];
    const float* b_hh_d  = (const float*)d_in[15];
    const float* W_fc    = (const float*)d_in[16];
    const float* b_fc    = (const float*)d_in[17];
    float* out = (float*)d_out;

    // ---------------- workspace layout (fused path) ----------------
    char* base = (char*)d_ws;
    size_t off = 0;
    auto alloc = [&](size_t bytes) { char* p = base + off; off += (bytes + 255) & ~(size_t)255; return p; };

    // ping-pong encoder h buffers: [f32 | hi | lo] contiguous per buffer
    float*   hEf[2]; ushortT* hEhi[2]; ushortT* hElo[2];
    for (int i = 0; i < 2; ++i) {
        hEf[i]  = (float*)  alloc((size_t)2 * B * H * 4);
        hEhi[i] = (ushortT*)alloc((size_t)2 * B * H * 2);
        hElo[i] = (ushortT*)alloc((size_t)2 * B * H * 2);
    }
    float*   hhf[2]; ushortT* hhhi[2]; ushortT* hhlo[2];
    for (int i = 0; i < 2; ++i) {
        hhf[i]  = (float*)  alloc((size_t)B * H2 * 4);
        hhhi[i] = (ushortT*)alloc((size_t)B * H2 * 2);
        hhlo[i] = (ushortT*)alloc((size_t)B * H2 * 2);
    }
    float*   giTabF = (float*)  alloc((size_t)VOUTD * H3 * 4);
    float*   giTabB = (float*)  alloc((size_t)VOUTD * H3 * 4);
    float*   giTabD = (float*)  alloc((size_t)VOUTD * H6 * 4);
    ushortT* Whhf_hi = (ushortT*)alloc((size_t)H3 * H * 2);
    ushortT* Whhf_lo = (ushortT*)alloc((size_t)H3 * H * 2);
    ushortT* Whhb_hi = (ushortT*)alloc((size_t)H3 * H * 2);
    ushortT* Whhb_lo = (ushortT*)alloc((size_t)H3 * H * 2);
    ushortT* Whhd_hi = (ushortT*)alloc((size_t)H6 * H2 * 2);
    ushortT* Whhd_lo = (ushortT*)alloc((size_t)H6 * H2 * 2);
    int*     tok    = (int*)    alloc((size_t)B * 4);
    size_t required = off;

    dim3 blk(256);

    if (ws_size >= required) {
        // =================== fused split-bf16 MFMA path ===================
        {   // zero h-enc buffer 0 (f32+hi+lo contiguous, 8 MB)
            size_t zbytes = (size_t)2 * B * H * 4 + 2 * ((size_t)2 * B * H * 2);
            int n16 = (int)(zbytes / 16);
            zero16<<<dim3((n16 + 255) / 256), blk, 0, stream>>>((uint4*)hEf[0], n16);
        }
        auto split = [&](const float* x, ushortT* hi, ushortT* lo, size_t n) {
            int n4 = (int)(n / 4);
            split_bf16<<<dim3((n4 + 255) / 256), blk, 0, stream>>>(
                (const float4*)x, (uint2*)hi, (uint2*)lo, n4);
        };
        split(W_hh_f, Whhf_hi, Whhf_lo, (size_t)H3 * H);
        split(W_hh_b, Whhb_hi, Whhb_lo, (size_t)H3 * H);
        split(W_hh_d, Whhd_hi, Whhd_lo, (size_t)H6 * H2);

        // gi tables (exact fp32): emb @ W_ih^T + b_ih, M=128
        gemm_bias<<<dim3(H3 / 64, VOUTD / 64), blk, 0, stream>>>(
            enc_emb, nullptr, 0, 0, E, W_ih_f, b_ih_f, giTabF, H3, E);
        gemm_bias<<<dim3(H3 / 64, VOUTD / 64), blk, 0, stream>>>(
            enc_emb, nullptr, 0, 0, E, W_ih_b, b_ih_b, giTabB, H3, E);
        gemm_bias<<<dim3(H6 / 64, VOUTD / 64), blk, 0, stream>>>(
            dec_emb, nullptr, 0, 0, E, W_ih_d, b_ih_d, giTabD, H6, E);

        // ---------------- Encoder: 64 fused steps ----------------
        for (int s = 0; s < S; ++s) {
            int rb = s & 1, wb = 1 - rb;
            gru_step_enc<<<dim3(256), blk, 0, stream>>>(
                hEhi[rb], hElo[rb],
                Whhf_hi, Whhf_lo, Whhb_hi, Whhb_lo,
                giTabF, giTabB, src, s, b_hh_f, b_hh_b,
                hEf[rb], hEf[wb], hEhi[wb], hElo[wb]);
        }
        // after 64 steps (even), final h is in buffer 0
        init_hh_tok_split<<<dim3((B * H2) / 256), blk, 0, stream>>>(
            hEf[0], hEf[0] + (size_t)B * H, tgt, hhf[0], hhhi[0], hhlo[0], tok);

        // ---------------- Decoder: 31 fused steps ----------------
        for (int t = 0; t < T - 1; ++t) {
            int rb = t & 1, wb = 1 - rb;
            gru_step_dec<<<dim3(256), blk, 0, stream>>>(
                hhhi[rb], hhlo[rb], Whhd_hi, Whhd_lo,
                giTabD, tok, b_hh_d,
                hhf[rb], hhf[wb], hhhi[wb], hhlo[wb]);
            logits_argmax<<<dim3(B), dim3(128), 0, stream>>>(
                hhf[wb], W_fc, b_fc, out, tok, t);
        }
    } else {
        // =================== fp32 fallback (R1-proven path) ===================
        size_t foff = 0;
        auto falloc = [&](size_t bytes) { char* p = base + foff; foff += (bytes + 255) & ~(size_t)255; return p; };
        float* hE  = (float*)falloc((size_t)2 * B * H * 4);
        float* hh  = (float*)falloc((size_t)B * H2 * 4);
        float* giE = (float*)falloc((size_t)2 * B * H3 * 4);
        float* ghF = (float*)falloc((size_t)2 * B * H3 * 4);
        int*   ftok = (int*)falloc((size_t)B * 4);
        {
            size_t zbytes = (size_t)2 * B * H * 4;
            int n16 = (int)(zbytes / 16);
            zero16<<<dim3((n16 + 255) / 256), blk, 0, stream>>>((uint4*)hE, n16);
        }
        dim3 grid_gi(H3 / 64, (2 * B) / 64);
        dim3 grid_gate((2 * B * H) / 256);
        for (int s = 0; s < S; ++s) {
            gemm_enc<<<grid_gi, blk, 0, stream>>>(enc_emb, E, E, src, s,
                                                  W_ih_f, b_ih_f, W_ih_b, b_ih_b, giE, H3);
            gemm_enc<<<grid_gi, blk, 0, stream>>>(hE, H, H, nullptr, 0,
                                                  W_hh_f, b_hh_f, W_hh_b, b_hh_b, ghF, H3);
            gru_gate<<<grid_gate, blk, 0, stream>>>(giE, ghF, hE, H);
        }
        init_hh_tok<<<dim3((B * H2) / 256), blk, 0, stream>>>(hE, hE + (size_t)B * H, tgt, hh, ftok);
        dim3 grid_d(H6 / 64, B / 64);
        dim3 grid_dgate((B * H2) / 256);
        for (int t = 0; t < T - 1; ++t) {
            gemm_bias<<<grid_d, blk, 0, stream>>>(dec_emb, ftok, 1, 0, E,
                                                  W_ih_d, b_ih_d, giE, H6, E);
            gemm_bias<<<grid_d, blk, 0, stream>>>(hh, nullptr, 0, 0, H2,
                                                  W_hh_d, b_hh_d, ghF, H6, H2);
            gru_gate<<<grid_dgate, blk, 0, stream>>>(giE, ghF, hh, H2);
            logits_argmax<<<dim3(B), dim3(128), 0, stream>>>(hh, W_fc, b_fc, out, ftok, t);
        }
    }
}